// Round 1
// baseline (154.426 us; speedup 1.0000x reference)
//
#include <hip/hip_runtime.h>

// TransformerBlockQuantum: [128, 8192, 8] fp32 in/out.
// One thread processes T=8 tokens end-to-end in registers.
// Weights are wave-uniform -> s_load / SGPR operands (no LDS, no per-lane loads).

#define NTOK   (128 * 8192)              // 1048576 tokens
#define T      8
#define NTHREADS 256
#define NBLOCKS  (NTOK / (T * NTHREADS)) // 512
#define TSTRIDE  (NTOK / T)              // 131072
#define LN_EPS 1e-5f

__device__ __forceinline__ float fast_cos(float x) {
    // v_cos_f32 takes revolutions; |x| here is < ~2 revolutions (domain +-256).
    return __builtin_amdgcn_cosf(x * 0.15915494309189535f);
}

__global__ __launch_bounds__(NTHREADS, 2)
void qtb_kernel(const float* __restrict__ x,
                const float* __restrict__ Wq,  const float* __restrict__ bq,
                const float* __restrict__ tha,
                const float* __restrict__ Wc,  const float* __restrict__ bc,
                const float* __restrict__ g1,  const float* __restrict__ be1,
                const float* __restrict__ thf,
                const float* __restrict__ W1,  const float* __restrict__ b1,
                const float* __restrict__ W2,  const float* __restrict__ b2,
                const float* __restrict__ g2,  const float* __restrict__ be2,
                float* __restrict__ out)
{
    const int g = blockIdx.x * NTHREADS + threadIdx.x;  // 0 .. 131071

    // ---- load x: 8 tokens * 8 feats, coalesced float4 pairs ----
    float xv[T][8];
#pragma unroll
    for (int t = 0; t < T; ++t) {
        const float4* p = reinterpret_cast<const float4*>(x) + (size_t)(t * TSTRIDE + g) * 2;
        float4 a = p[0];
        float4 b = p[1];
        xv[t][0] = a.x; xv[t][1] = a.y; xv[t][2] = a.z; xv[t][3] = a.w;
        xv[t][4] = b.x; xv[t][5] = b.y; xv[t][6] = b.z; xv[t][7] = b.w;
    }

    // ---- attention: q = x@Wq+bq, ca = cos(q+tha), z via cumprods, attn = z@Wc+bc ----
    float attn[T][8];
#pragma unroll
    for (int t = 0; t < T; ++t)
#pragma unroll
        for (int j = 0; j < 8; ++j) attn[t][j] = bc[j];

    float cp[T];   // running prod ca[0..k]
    float cp1[T];  // running prod ca[1..k]  (for z0)
#pragma unroll
    for (int k = 0; k < 8; ++k) {
        const float bqk = bq[k];
        const float thk = tha[k];
        float wq[8], wc[8];
#pragma unroll
        for (int i = 0; i < 8; ++i) wq[i] = Wq[i * 8 + k];   // column k of Wq
#pragma unroll
        for (int j = 0; j < 8; ++j) wc[j] = Wc[k * 8 + j];   // row k of Wc
#pragma unroll
        for (int t = 0; t < T; ++t) {
            float q = bqk;
#pragma unroll
            for (int i = 0; i < 8; ++i) q += xv[t][i] * wq[i];
            float ca = fast_cos(q + thk);
            if (k == 0) {
                cp[t] = ca;
                cp1[t] = 1.0f;
            } else {
                cp[t]  *= ca;
                cp1[t] *= ca;
                // z[k] = prod_{j=0..k} ca_j  contributes to attn via Wc row k
#pragma unroll
                for (int j = 0; j < 8; ++j) attn[t][j] += cp[t] * wc[j];
            }
        }
    }
    // z[0] = prod_{j=1..7} ca_j contributes via Wc row 0
    {
        float wc0[8];
#pragma unroll
        for (int j = 0; j < 8; ++j) wc0[j] = Wc[j];
#pragma unroll
        for (int t = 0; t < T; ++t)
#pragma unroll
            for (int j = 0; j < 8; ++j) attn[t][j] += cp1[t] * wc0[j];
    }

    // ---- LN1 (over 8 feats, thread-local) + zf = cos(thf) * cos(x1) ----
    float cf[8];
#pragma unroll
    for (int j = 0; j < 8; ++j) cf[j] = fast_cos(thf[j]);
    float sg1[8], sb1[8];
#pragma unroll
    for (int j = 0; j < 8; ++j) { sg1[j] = g1[j]; sb1[j] = be1[j]; }

    float zf[T][8];
#pragma unroll
    for (int t = 0; t < T; ++t) {
        float y[8];
        float s = 0.f;
#pragma unroll
        for (int j = 0; j < 8; ++j) { y[j] = xv[t][j] + attn[t][j]; s += y[j]; }
        float m = s * 0.125f;
        float v = 0.f;
#pragma unroll
        for (int j = 0; j < 8; ++j) { float d = y[j] - m; v += d * d; }
        float r = rsqrtf(v * 0.125f + LN_EPS);
#pragma unroll
        for (int j = 0; j < 8; ++j) {
            float x1 = (y[j] - m) * r * sg1[j] + sb1[j];
            xv[t][j] = x1;                       // keep x1 for residual 2
            zf[t][j] = cf[j] * fast_cos(x1);
        }
    }

    // ---- FFN: h = relu(zf@W1 + b1); ffn = h@W2 + b2 (h never materialized fully) ----
    float ffn[T][8];
    {
        float sb2[8];
#pragma unroll
        for (int j = 0; j < 8; ++j) sb2[j] = b2[j];
#pragma unroll
        for (int t = 0; t < T; ++t)
#pragma unroll
            for (int j = 0; j < 8; ++j) ffn[t][j] = sb2[j];
    }
#pragma unroll
    for (int m = 0; m < 32; ++m) {
        const float b1m = b1[m];
        float w1[8], w2[8];
#pragma unroll
        for (int i = 0; i < 8; ++i) w1[i] = W1[i * 32 + m];  // column m of W1
#pragma unroll
        for (int j = 0; j < 8; ++j) w2[j] = W2[m * 8 + j];   // row m of W2
#pragma unroll
        for (int t = 0; t < T; ++t) {
            float h = b1m;
#pragma unroll
            for (int i = 0; i < 8; ++i) h += zf[t][i] * w1[i];
            h = fmaxf(h, 0.f);
#pragma unroll
            for (int j = 0; j < 8; ++j) ffn[t][j] += h * w2[j];
        }
    }

    // ---- LN2 + store ----
    float sg2[8], sbb2[8];
#pragma unroll
    for (int j = 0; j < 8; ++j) { sg2[j] = g2[j]; sbb2[j] = be2[j]; }
#pragma unroll
    for (int t = 0; t < T; ++t) {
        float y[8];
        float s = 0.f;
#pragma unroll
        for (int j = 0; j < 8; ++j) { y[j] = xv[t][j] + ffn[t][j]; s += y[j]; }
        float m = s * 0.125f;
        float v = 0.f;
#pragma unroll
        for (int j = 0; j < 8; ++j) { float d = y[j] - m; v += d * d; }
        float r = rsqrtf(v * 0.125f + LN_EPS);
        float o[8];
#pragma unroll
        for (int j = 0; j < 8; ++j) o[j] = (y[j] - m) * r * sg2[j] + sbb2[j];
        float4* q = reinterpret_cast<float4*>(out) + (size_t)(t * TSTRIDE + g) * 2;
        q[0] = make_float4(o[0], o[1], o[2], o[3]);
        q[1] = make_float4(o[4], o[5], o[6], o[7]);
    }
}

extern "C" void kernel_launch(void* const* d_in, const int* in_sizes, int n_in,
                              void* d_out, int out_size, void* d_ws, size_t ws_size,
                              hipStream_t stream) {
    (void)in_sizes; (void)n_in; (void)d_ws; (void)ws_size; (void)out_size;
    qtb_kernel<<<NBLOCKS, NTHREADS, 0, stream>>>(
        (const float*)d_in[0],  // x
        (const float*)d_in[1],  // Wq
        (const float*)d_in[2],  // bq
        (const float*)d_in[3],  // theta_attn
        (const float*)d_in[4],  // Wc
        (const float*)d_in[5],  // bc
        (const float*)d_in[6],  // g1
        (const float*)d_in[7],  // beta1
        (const float*)d_in[8],  // theta_ffn
        (const float*)d_in[9],  // W1
        (const float*)d_in[10], // b1
        (const float*)d_in[11], // W2
        (const float*)d_in[12], // b2
        (const float*)d_in[13], // g2
        (const float*)d_in[14], // beta2
        (float*)d_out);
}

// Round 2
// 137.426 us; speedup vs baseline: 1.1237x; 1.1237x over previous
//
#include <hip/hip_runtime.h>

// TransformerBlockQuantum: [128, 8192, 8] fp32 in/out.
// One thread processes T=2 tokens end-to-end in registers.
// Weights are wave-uniform -> s_load / SGPR operands (no LDS, no per-lane loads).
// R2: T=8->2 for occupancy (19% -> target ~75%); was latency-bound at 8 waves/CU.

#define NTOK   (128 * 8192)              // 1048576 tokens
#define T      2
#define NTHREADS 256
#define NBLOCKS  (NTOK / (T * NTHREADS)) // 2048
#define TSTRIDE  (NTOK / T)              // 524288
#define LN_EPS 1e-5f

__device__ __forceinline__ float fast_cos(float x) {
    // v_cos_f32 takes revolutions; |x| here is < ~2 revolutions (domain +-256).
    return __builtin_amdgcn_cosf(x * 0.15915494309189535f);
}

__global__ __launch_bounds__(NTHREADS, 6)
void qtb_kernel(const float* __restrict__ x,
                const float* __restrict__ Wq,  const float* __restrict__ bq,
                const float* __restrict__ tha,
                const float* __restrict__ Wc,  const float* __restrict__ bc,
                const float* __restrict__ g1,  const float* __restrict__ be1,
                const float* __restrict__ thf,
                const float* __restrict__ W1,  const float* __restrict__ b1,
                const float* __restrict__ W2,  const float* __restrict__ b2,
                const float* __restrict__ g2,  const float* __restrict__ be2,
                float* __restrict__ out)
{
    const int g = blockIdx.x * NTHREADS + threadIdx.x;  // 0 .. TSTRIDE-1

    // ---- load x: T tokens * 8 feats, coalesced float4 pairs ----
    float xv[T][8];
#pragma unroll
    for (int t = 0; t < T; ++t) {
        const float4* p = reinterpret_cast<const float4*>(x) + (size_t)(t * TSTRIDE + g) * 2;
        float4 a = p[0];
        float4 b = p[1];
        xv[t][0] = a.x; xv[t][1] = a.y; xv[t][2] = a.z; xv[t][3] = a.w;
        xv[t][4] = b.x; xv[t][5] = b.y; xv[t][6] = b.z; xv[t][7] = b.w;
    }

    // ---- attention: q = x@Wq+bq, ca = cos(q+tha), z via cumprods, attn = z@Wc+bc ----
    float attn[T][8];
#pragma unroll
    for (int t = 0; t < T; ++t)
#pragma unroll
        for (int j = 0; j < 8; ++j) attn[t][j] = bc[j];

    float cp[T];   // running prod ca[0..k]
    float cp1[T];  // running prod ca[1..k]  (for z0)
#pragma unroll
    for (int k = 0; k < 8; ++k) {
        const float bqk = bq[k];
        const float thk = tha[k];
        float wq[8], wc[8];
#pragma unroll
        for (int i = 0; i < 8; ++i) wq[i] = Wq[i * 8 + k];   // column k of Wq
#pragma unroll
        for (int j = 0; j < 8; ++j) wc[j] = Wc[k * 8 + j];   // row k of Wc
#pragma unroll
        for (int t = 0; t < T; ++t) {
            float q = bqk;
#pragma unroll
            for (int i = 0; i < 8; ++i) q += xv[t][i] * wq[i];
            float ca = fast_cos(q + thk);
            if (k == 0) {
                cp[t] = ca;
                cp1[t] = 1.0f;
            } else {
                cp[t]  *= ca;
                cp1[t] *= ca;
                // z[k] = prod_{j=0..k} ca_j  contributes to attn via Wc row k
#pragma unroll
                for (int j = 0; j < 8; ++j) attn[t][j] += cp[t] * wc[j];
            }
        }
    }
    // z[0] = prod_{j=1..7} ca_j contributes via Wc row 0
    {
        float wc0[8];
#pragma unroll
        for (int j = 0; j < 8; ++j) wc0[j] = Wc[j];
#pragma unroll
        for (int t = 0; t < T; ++t)
#pragma unroll
            for (int j = 0; j < 8; ++j) attn[t][j] += cp1[t] * wc0[j];
    }

    // ---- LN1 (over 8 feats, thread-local) + zf = cos(thf) * cos(x1) ----
    float cf[8];
#pragma unroll
    for (int j = 0; j < 8; ++j) cf[j] = fast_cos(thf[j]);
    float sg1[8], sb1[8];
#pragma unroll
    for (int j = 0; j < 8; ++j) { sg1[j] = g1[j]; sb1[j] = be1[j]; }

    float zf[T][8];
#pragma unroll
    for (int t = 0; t < T; ++t) {
        float y[8];
        float s = 0.f;
#pragma unroll
        for (int j = 0; j < 8; ++j) { y[j] = xv[t][j] + attn[t][j]; s += y[j]; }
        float m = s * 0.125f;
        float v = 0.f;
#pragma unroll
        for (int j = 0; j < 8; ++j) { float d = y[j] - m; v += d * d; }
        float r = rsqrtf(v * 0.125f + LN_EPS);
#pragma unroll
        for (int j = 0; j < 8; ++j) {
            float x1 = (y[j] - m) * r * sg1[j] + sb1[j];
            xv[t][j] = x1;                       // keep x1 for residual 2
            zf[t][j] = cf[j] * fast_cos(x1);
        }
    }

    // ---- FFN: h = relu(zf@W1 + b1); ffn = h@W2 + b2 (h never materialized fully) ----
    float ffn[T][8];
    {
        float sb2[8];
#pragma unroll
        for (int j = 0; j < 8; ++j) sb2[j] = b2[j];
#pragma unroll
        for (int t = 0; t < T; ++t)
#pragma unroll
            for (int j = 0; j < 8; ++j) ffn[t][j] = sb2[j];
    }
#pragma unroll
    for (int m = 0; m < 32; ++m) {
        const float b1m = b1[m];
        float w1[8], w2[8];
#pragma unroll
        for (int i = 0; i < 8; ++i) w1[i] = W1[i * 32 + m];  // column m of W1
#pragma unroll
        for (int j = 0; j < 8; ++j) w2[j] = W2[m * 8 + j];   // row m of W2
#pragma unroll
        for (int t = 0; t < T; ++t) {
            float h = b1m;
#pragma unroll
            for (int i = 0; i < 8; ++i) h += zf[t][i] * w1[i];
            h = fmaxf(h, 0.f);
#pragma unroll
            for (int j = 0; j < 8; ++j) ffn[t][j] += h * w2[j];
        }
    }

    // ---- LN2 + store ----
    float sg2[8], sbb2[8];
#pragma unroll
    for (int j = 0; j < 8; ++j) { sg2[j] = g2[j]; sbb2[j] = be2[j]; }
#pragma unroll
    for (int t = 0; t < T; ++t) {
        float y[8];
        float s = 0.f;
#pragma unroll
        for (int j = 0; j < 8; ++j) { y[j] = xv[t][j] + ffn[t][j]; s += y[j]; }
        float m = s * 0.125f;
        float v = 0.f;
#pragma unroll
        for (int j = 0; j < 8; ++j) { float d = y[j] - m; v += d * d; }
        float r = rsqrtf(v * 0.125f + LN_EPS);
        float o[8];
#pragma unroll
        for (int j = 0; j < 8; ++j) o[j] = (y[j] - m) * r * sg2[j] + sbb2[j];
        float4* q = reinterpret_cast<float4*>(out) + (size_t)(t * TSTRIDE + g) * 2;
        q[0] = make_float4(o[0], o[1], o[2], o[3]);
        q[1] = make_float4(o[4], o[5], o[6], o[7]);
    }
}

extern "C" void kernel_launch(void* const* d_in, const int* in_sizes, int n_in,
                              void* d_out, int out_size, void* d_ws, size_t ws_size,
                              hipStream_t stream) {
    (void)in_sizes; (void)n_in; (void)d_ws; (void)ws_size; (void)out_size;
    qtb_kernel<<<NBLOCKS, NTHREADS, 0, stream>>>(
        (const float*)d_in[0],  // x
        (const float*)d_in[1],  // Wq
        (const float*)d_in[2],  // bq
        (const float*)d_in[3],  // theta_attn
        (const float*)d_in[4],  // Wc
        (const float*)d_in[5],  // bc
        (const float*)d_in[6],  // g1
        (const float*)d_in[7],  // beta1
        (const float*)d_in[8],  // theta_ffn
        (const float*)d_in[9],  // W1
        (const float*)d_in[10], // b1
        (const float*)d_in[11], // W2
        (const float*)d_in[12], // b2
        (const float*)d_in[13], // g2
        (const float*)d_in[14], // beta2
        (float*)d_out);
}